// Round 9
// baseline (246.800 us; speedup 1.0000x reference)
//
#include <hip/hip_runtime.h>
#include <math.h>

#define Nn 20000
#define Ee 320000
#define Dd 300
#define Hh 2
#define Cc 600    // Hh*Dd
#define KP 320    // K padded to multiple of 32
#define MP 20096  // M padded to 157*128
#define NP 640    // N padded to 5*128
#define SQ 640    // xq row stride (elems): 1280 B, 16B-aligned rows

typedef _Float16 f16;
typedef __attribute__((ext_vector_type(8))) _Float16 f16x8;
typedef __attribute__((ext_vector_type(4))) _Float16 f16x4;
typedef __attribute__((ext_vector_type(4))) float f32x4;

__device__ __forceinline__ float lrelu(float x) { return x > 0.f ? x : 0.2f * x; }

#define GLDS16(src, dst)                                                            \
  __builtin_amdgcn_global_load_lds(                                                 \
      (const __attribute__((address_space(1))) unsigned int*)(src),                 \
      (__attribute__((address_space(3))) unsigned int*)(dst), 16, 0, 0)

// ---------------- k_pre2: Wh (transposed fp16) + vatt + zero cnt/dsum ----------------
__global__ __launch_bounds__(256) void k_pre2(const float* __restrict__ W,
                                              const float* __restrict__ att_src,
                                              const float* __restrict__ att_dst,
                                              f16* __restrict__ Wh, float* __restrict__ vatt,
                                              int* __restrict__ cnt, float* __restrict__ dsum) {
  int idx = blockIdx.x * 256 + threadIdx.x;  // grid: NP*KP/4 = 51200 threads
  if (idx < Nn) {
    cnt[idx] = 0;
    *(float2*)(dsum + 2 * idx) = make_float2(0.f, 0.f);
  }
  {
    int c = idx % NP, k0 = (idx / NP) * 4;
    f16x4 h;
#pragma unroll
    for (int j = 0; j < 4; ++j) {
      int k = k0 + j;
      h[j] = (f16)((k < Dd && c < Cc) ? W[(size_t)k * Cc + c] : 0.f);
    }
    *(f16x4*)(Wh + (size_t)c * KP + k0) = h;
  }
  int wid = idx >> 6, ln = idx & 63;
  if (wid < Dd) {
    float s0 = 0.f, s1 = 0.f, t0 = 0.f, t1 = 0.f;
    for (int e = ln; e < Dd; e += 64) {
      float w0 = W[(size_t)wid * Cc + e];
      float w1 = W[(size_t)wid * Cc + Dd + e];
      s0 += w0 * att_src[e];  s1 += w1 * att_src[Dd + e];
      t0 += w0 * att_dst[e];  t1 += w1 * att_dst[Dd + e];
    }
    for (int o = 32; o > 0; o >>= 1) {
      s0 += __shfl_down(s0, o, 64); s1 += __shfl_down(s1, o, 64);
      t0 += __shfl_down(t0, o, 64); t1 += __shfl_down(t1, o, 64);
    }
    if (ln == 0) {
      vatt[wid * 4 + 0] = s0; vatt[wid * 4 + 1] = s1;
      vatt[wid * 4 + 2] = t0; vatt[wid * 4 + 3] = t1;
    }
  }
}

// ---------------- k_pre1: xh (fp16, padded) + logits + edge histogram ----------------
__global__ __launch_bounds__(256) void k_pre1(const float* __restrict__ x,
                                              const float* __restrict__ vatt,
                                              const int* __restrict__ ei,
                                              f16* __restrict__ xh,
                                              float* __restrict__ a_src, float* __restrict__ a_dst,
                                              int* __restrict__ cnt) {
  int gid = blockIdx.x * 256 + threadIdx.x;  // 5024*256 = 1,286,144 >= Ee
  if (gid < Ee) atomicAdd(&cnt[ei[Ee + gid]], 1);
  int wv = threadIdx.x >> 6, ln = threadIdx.x & 63;
  int n = blockIdx.x * 4 + wv;
  if (n >= MP) return;
  if (n >= Nn) {  // zero-fill pad rows for k_mm
#pragma unroll
    for (int k = 0; k < 5; ++k) xh[(size_t)n * KP + ln + 64 * k] = (f16)0.f;
    return;
  }
  const float* xr = x + (size_t)n * Dd;
  float s0 = 0.f, s1 = 0.f, t0 = 0.f, t1 = 0.f;
#pragma unroll
  for (int k = 0; k < 5; ++k) {
    int d = ln + 64 * k;  // 0..319
    float xv = 0.f;
    if (d < Dd) {
      xv = xr[d];
      float4 vv = *(const float4*)(vatt + d * 4);
      s0 += xv * vv.x; s1 += xv * vv.y; t0 += xv * vv.z; t1 += xv * vv.w;
    }
    xh[(size_t)n * KP + d] = (f16)xv;
  }
  for (int o = 32; o > 0; o >>= 1) {
    s0 += __shfl_down(s0, o, 64); s1 += __shfl_down(s1, o, 64);
    t0 += __shfl_down(t0, o, 64); t1 += __shfl_down(t1, o, 64);
  }
  if (ln == 0) {
    a_src[n * 2 + 0] = s0; a_src[n * 2 + 1] = s1;
    a_dst[n * 2 + 0] = t0; a_dst[n * 2 + 1] = t1;
  }
}

// ---------------- MFMA GEMM, m97 structure: 128x128 tile, global_load_lds, swizzled LDS ----------------
__global__ __launch_bounds__(256) void k_mm(const f16* __restrict__ xh, const f16* __restrict__ Wh,
                                            f16* __restrict__ xq) {
  __shared__ __align__(16) f16 As[128 * 32];
  __shared__ __align__(16) f16 Bs[128 * 32];
  int m0 = blockIdx.x * 128, n0 = blockIdx.y * 128;
  int tid = threadIdx.x, wv = tid >> 6, lane = tid & 63;
  int wr = wv >> 1, wc = wv & 1;

  int r0a = 32 * wv + (lane >> 2);
  int ca  = ((lane & 3) ^ ((r0a >> 1) & 3)) * 8;
  int r0b = r0a + 16;
  int cb  = ((lane & 3) ^ ((r0b >> 1) & 3)) * 8;

  f32x4 acc[4][4] = {};
  for (int ks = 0; ks < KP / 32; ++ks) {
    __syncthreads();
    GLDS16(xh + (size_t)(m0 + r0a) * KP + ks * 32 + ca, As + (32 * wv) * 32);
    GLDS16(xh + (size_t)(m0 + r0b) * KP + ks * 32 + cb, As + (32 * wv + 16) * 32);
    GLDS16(Wh + (size_t)(n0 + r0a) * KP + ks * 32 + ca, Bs + (32 * wv) * 32);
    GLDS16(Wh + (size_t)(n0 + r0b) * KP + ks * 32 + cb, Bs + (32 * wv + 16) * 32);
    __syncthreads();

    f16x8 af[4], bf[4];
#pragma unroll
    for (int i = 0; i < 4; ++i) {
      int rA = wr * 64 + i * 16 + (lane & 15);
      int sA = (lane >> 4) ^ ((rA >> 1) & 3);
      af[i] = *(const f16x8*)&As[rA * 32 + sA * 8];
      int rB = wc * 64 + i * 16 + (lane & 15);
      int sB = (lane >> 4) ^ ((rB >> 1) & 3);
      bf[i] = *(const f16x8*)&Bs[rB * 32 + sB * 8];
    }
#pragma unroll
    for (int i = 0; i < 4; ++i)
#pragma unroll
      for (int j = 0; j < 4; ++j)
        acc[i][j] = __builtin_amdgcn_mfma_f32_16x16x32_f16(af[i], bf[j], acc[i][j], 0, 0, 0);
  }

#pragma unroll
  for (int i = 0; i < 4; ++i) {
#pragma unroll
    for (int j = 0; j < 4; ++j) {
      int col = n0 + wc * 64 + j * 16 + (lane & 15);
      if (col < Cc) {
        int rbase = m0 + wr * 64 + i * 16 + ((lane >> 4) * 4);
#pragma unroll
        for (int r = 0; r < 4; ++r) {
          int row = rbase + r;
          if (row < Nn) xq[(size_t)row * SQ + col] = (f16)acc[i][j][r];
        }
      }
    }
  }
}

// ---------------- single-block scan: thread owns 20 contiguous counts ----------------
__global__ __launch_bounds__(1024) void k_scan(const int* __restrict__ cnt,
                                               int* __restrict__ offs, int* __restrict__ cur) {
  __shared__ int wsum[16];
  int t = threadIdx.x, wv = t >> 6, ln = t & 63;
  int i0 = t * 20;
  int v[20];
  int tot = 0;
  if (i0 < Nn) {
    const int4* p = (const int4*)(cnt + i0);
#pragma unroll
    for (int q = 0; q < 5; ++q) {
      int4 w = p[q];
      v[4 * q] = w.x; v[4 * q + 1] = w.y; v[4 * q + 2] = w.z; v[4 * q + 3] = w.w;
    }
#pragma unroll
    for (int j = 0; j < 20; ++j) tot += v[j];
  }
  int s = tot;
  for (int o = 1; o < 64; o <<= 1) {
    int u = __shfl_up(s, o, 64);
    if (ln >= o) s += u;
  }
  if (ln == 63) wsum[wv] = s;
  __syncthreads();
  if (wv == 0) {
    int w = (ln < 16) ? wsum[ln] : 0;
    for (int o = 1; o < 16; o <<= 1) {
      int u = __shfl_up(w, o, 64);
      if (ln >= o) w += u;
    }
    if (ln < 16) wsum[ln] = w;
  }
  __syncthreads();
  if (i0 < Nn) {
    int run = (wv > 0 ? wsum[wv - 1] : 0) + (s - tot);
#pragma unroll
    for (int j = 0; j < 20; ++j) {
      offs[i0 + j] = run;
      cur[i0 + j] = run;
      run += v[j];
    }
  }
  if (t == 0) offs[Nn] = wsum[15];
}

// ---------------- scatter: sorted edge records {src, e0, e1} + denominator atomics ----------------
__global__ void k_scatter(const int* __restrict__ ei,
                          const float* __restrict__ a_src, const float* __restrict__ a_dst,
                          int* __restrict__ cur, float* __restrict__ dsum,
                          float4* __restrict__ erec) {
  int e = blockIdx.x * 256 + threadIdx.x;
  if (e < Ee) {
    int s = ei[e], d = ei[Ee + e];
    float2 av = *(const float2*)(a_src + 2 * s);
    float2 bv = *(const float2*)(a_dst + 2 * d);
    float e0 = __expf(lrelu(av.x + bv.x));
    float e1 = __expf(lrelu(av.y + bv.y));
    int pos = atomicAdd(&cur[d], 1);
    erec[pos] = make_float4(__int_as_float(s), e0, e1, 0.f);
    atomicAdd(&dsum[2 * d + 0], e0);
    atomicAdd(&dsum[2 * d + 1], e1);
  }
}

// ---------------- wave-per-node: pure gather-FMA aggregation + epilogue ----------------
__global__ __launch_bounds__(256) void k_agg(const f16* __restrict__ xq,
    const float4* __restrict__ erec,
    const float* __restrict__ a_src, const float* __restrict__ a_dst,
    const float* __restrict__ dsum, const int* __restrict__ offs,
    const float* __restrict__ bias, const float* __restrict__ lin_w,
    const float* __restrict__ lin_b, float* __restrict__ out) {
  __shared__ float sAgg[4][600];
  int tid = threadIdx.x, wv = tid >> 6, ln = tid & 63;
  int n = blockIdx.x * 4 + wv;
  int beg = offs[n], deg = offs[n + 1] - beg;
  float2 adv = *(const float2*)(a_dst + 2 * n);
  float2 asv = *(const float2*)(a_src + 2 * n);
  float sw0 = __expf(lrelu(asv.x + adv.x));
  float sw1 = __expf(lrelu(asv.y + adv.y));
  float2 dv = *(const float2*)(dsum + 2 * n);
  float inv0 = 1.f / (dv.x + sw0), inv1 = 1.f / (dv.y + sw1);

  float acc[12] = {};
  auto addrow = [&](const f16* row, float p0, float p1) {
#pragma unroll
    for (int k = 0; k < 3; ++k) {
      int c = 4 * ln + 256 * k;  // head split at 300 is 4-aligned
      if (c < Cc) {
        f16x4 hv = *(const f16x4*)(row + c);
        float p = (c < Dd) ? p0 : p1;
        acc[4 * k + 0] += p * (float)hv[0];
        acc[4 * k + 1] += p * (float)hv[1];
        acc[4 * k + 2] += p * (float)hv[2];
        acc[4 * k + 3] += p * (float)hv[3];
      }
    }
  };

  int j = 0;
  for (; j + 4 <= deg; j += 4) {  // wave-uniform 16B broadcast loads, 4 rows in flight
    float4 r0 = erec[beg + j + 0];
    float4 r1 = erec[beg + j + 1];
    float4 r2 = erec[beg + j + 2];
    float4 r3 = erec[beg + j + 3];
    addrow(xq + (size_t)__float_as_int(r0.x) * SQ, r0.y * inv0, r0.z * inv1);
    addrow(xq + (size_t)__float_as_int(r1.x) * SQ, r1.y * inv0, r1.z * inv1);
    addrow(xq + (size_t)__float_as_int(r2.x) * SQ, r2.y * inv0, r2.z * inv1);
    addrow(xq + (size_t)__float_as_int(r3.x) * SQ, r3.y * inv0, r3.z * inv1);
  }
  for (; j < deg; ++j) {
    float4 r = erec[beg + j];
    addrow(xq + (size_t)__float_as_int(r.x) * SQ, r.y * inv0, r.z * inv1);
  }
  addrow(xq + (size_t)n * SQ, sw0 * inv0, sw1 * inv1);  // self-loop

#pragma unroll
  for (int k = 0; k < 3; ++k) {
    int c = 4 * ln + 256 * k;
    if (c < Cc) {
#pragma unroll
      for (int q = 0; q < 4; ++q) sAgg[wv][c + q] = acc[4 * k + q];
    }
  }
  __syncthreads();

  float part = 0.f;
#pragma unroll
  for (int k = 0; k < 5; ++k) {
    int d = ln + 64 * k;
    if (d < Dd) {
      float v = 0.5f * (sAgg[wv][d] + sAgg[wv][d + Dd]) + bias[d];
      v = fmaxf(v, 0.f);
      part += v * lin_w[d];
    }
  }
  for (int o = 32; o > 0; o >>= 1) part += __shfl_xor(part, o, 64);
  if (ln == 0) out[n] = part + lin_b[0];
}

extern "C" void kernel_launch(void* const* d_in, const int* in_sizes, int n_in,
                              void* d_out, int out_size, void* d_ws, size_t ws_size,
                              hipStream_t stream) {
  const float* x       = (const float*)d_in[0];
  const int*   ei      = (const int*)d_in[1];
  const float* W       = (const float*)d_in[2];
  const float* att_src = (const float*)d_in[3];
  const float* att_dst = (const float*)d_in[4];
  const float* bias    = (const float*)d_in[5];
  const float* lin_w   = (const float*)d_in[6];
  const float* lin_b   = (const float*)d_in[7];
  float* out = (float*)d_out;

  char* ws = (char*)d_ws;
  size_t off = 0;
  auto alloc = [&](size_t bytes) {
    void* p = ws + off;
    off = (off + bytes + 255) & ~(size_t)255;
    return p;
  };
  f16*    xq    = (f16*)alloc((size_t)Nn * SQ * 2);
  f16*    xh    = (f16*)alloc((size_t)MP * KP * 2);
  f16*    Wh    = (f16*)alloc((size_t)NP * KP * 2);
  float*  vatt  = (float*)alloc((size_t)Dd * 4 * 4);
  float*  a_src = (float*)alloc((size_t)Nn * Hh * 4);
  float*  a_dst = (float*)alloc((size_t)Nn * Hh * 4);
  int*    cnt   = (int*)alloc((size_t)Nn * 4);
  int*    offs  = (int*)alloc((size_t)(Nn + 1) * 4);
  int*    cur   = (int*)alloc((size_t)Nn * 4);
  float*  dsum  = (float*)alloc((size_t)Nn * 2 * 4);
  float4* erec  = (float4*)alloc((size_t)Ee * 16);

  k_pre2<<<NP * (KP / 4) / 256, 256, 0, stream>>>(W, att_src, att_dst, Wh, vatt, cnt, dsum);
  k_pre1<<<MP / 4, 256, 0, stream>>>(x, vatt, ei, xh, a_src, a_dst, cnt);
  k_mm<<<dim3(MP / 128, NP / 128), 256, 0, stream>>>(xh, Wh, xq);
  k_scan<<<1, 1024, 0, stream>>>(cnt, offs, cur);
  k_scatter<<<(Ee + 255) / 256, 256, 0, stream>>>(ei, a_src, a_dst, cur, dsum, erec);
  k_agg<<<Nn / 4, 256, 0, stream>>>(xq, erec, a_src, a_dst, dsum, offs, bias, lin_w, lin_b, out);
}

// Round 10
// 222.431 us; speedup vs baseline: 1.1096x; 1.1096x over previous
//
#include <hip/hip_runtime.h>
#include <math.h>

#define Nn 20000
#define Ee 320000
#define Dd 300
#define Hh 2
#define Cc 600    // Hh*Dd
#define KP 320    // K padded to multiple of 32
#define MP 20096  // M padded to 157*128
#define NP 640    // N padded to 5*128
#define SQ 640    // xq row stride (elems): 1280 B, 16B-aligned rows

typedef _Float16 f16;
typedef __attribute__((ext_vector_type(8))) _Float16 f16x8;
typedef __attribute__((ext_vector_type(4))) _Float16 f16x4;
typedef __attribute__((ext_vector_type(4))) float f32x4;

__device__ __forceinline__ float lrelu(float x) { return x > 0.f ? x : 0.2f * x; }

#define GLDS16(src, dst)                                                            \
  __builtin_amdgcn_global_load_lds(                                                 \
      (const __attribute__((address_space(1))) unsigned int*)(src),                 \
      (__attribute__((address_space(3))) unsigned int*)(dst), 16, 0, 0)

// ---------------- k_pre2: Wh (transposed fp16) + vatt + zero cnt ----------------
__global__ __launch_bounds__(256) void k_pre2(const float* __restrict__ W,
                                              const float* __restrict__ att_src,
                                              const float* __restrict__ att_dst,
                                              f16* __restrict__ Wh, float* __restrict__ vatt,
                                              int* __restrict__ cnt) {
  int idx = blockIdx.x * 256 + threadIdx.x;  // grid: NP*KP/4 = 51200 threads
  if (idx < Nn) cnt[idx] = 0;
  {
    int c = idx % NP, k0 = (idx / NP) * 4;
    f16x4 h;
#pragma unroll
    for (int j = 0; j < 4; ++j) {
      int k = k0 + j;
      h[j] = (f16)((k < Dd && c < Cc) ? W[(size_t)k * Cc + c] : 0.f);
    }
    *(f16x4*)(Wh + (size_t)c * KP + k0) = h;
  }
  int wid = idx >> 6, ln = idx & 63;
  if (wid < Dd) {
    float s0 = 0.f, s1 = 0.f, t0 = 0.f, t1 = 0.f;
    for (int e = ln; e < Dd; e += 64) {
      float w0 = W[(size_t)wid * Cc + e];
      float w1 = W[(size_t)wid * Cc + Dd + e];
      s0 += w0 * att_src[e];  s1 += w1 * att_src[Dd + e];
      t0 += w0 * att_dst[e];  t1 += w1 * att_dst[Dd + e];
    }
    for (int o = 32; o > 0; o >>= 1) {
      s0 += __shfl_down(s0, o, 64); s1 += __shfl_down(s1, o, 64);
      t0 += __shfl_down(t0, o, 64); t1 += __shfl_down(t1, o, 64);
    }
    if (ln == 0) {
      vatt[wid * 4 + 0] = s0; vatt[wid * 4 + 1] = s1;
      vatt[wid * 4 + 2] = t0; vatt[wid * 4 + 3] = t1;
    }
  }
}

// ---------------- k_pre1: xh (fp16, padded) + logits + edge histogram ----------------
__global__ __launch_bounds__(256) void k_pre1(const float* __restrict__ x,
                                              const float* __restrict__ vatt,
                                              const int* __restrict__ ei,
                                              f16* __restrict__ xh,
                                              float* __restrict__ a_src, float* __restrict__ a_dst,
                                              int* __restrict__ cnt) {
  int gid = blockIdx.x * 256 + threadIdx.x;  // 5024*256 = 1,286,144 >= Ee
  if (gid < Ee) atomicAdd(&cnt[ei[Ee + gid]], 1);
  int wv = threadIdx.x >> 6, ln = threadIdx.x & 63;
  int n = blockIdx.x * 4 + wv;
  if (n >= MP) return;
  if (n >= Nn) {  // zero-fill pad rows for k_mm
#pragma unroll
    for (int k = 0; k < 5; ++k) xh[(size_t)n * KP + ln + 64 * k] = (f16)0.f;
    return;
  }
  const float* xr = x + (size_t)n * Dd;
  float s0 = 0.f, s1 = 0.f, t0 = 0.f, t1 = 0.f;
#pragma unroll
  for (int k = 0; k < 5; ++k) {
    int d = ln + 64 * k;  // 0..319
    float xv = 0.f;
    if (d < Dd) {
      xv = xr[d];
      float4 vv = *(const float4*)(vatt + d * 4);
      s0 += xv * vv.x; s1 += xv * vv.y; t0 += xv * vv.z; t1 += xv * vv.w;
    }
    xh[(size_t)n * KP + d] = (f16)xv;
  }
  for (int o = 32; o > 0; o >>= 1) {
    s0 += __shfl_down(s0, o, 64); s1 += __shfl_down(s1, o, 64);
    t0 += __shfl_down(t0, o, 64); t1 += __shfl_down(t1, o, 64);
  }
  if (ln == 0) {
    a_src[n * 2 + 0] = s0; a_src[n * 2 + 1] = s1;
    a_dst[n * 2 + 0] = t0; a_dst[n * 2 + 1] = t1;
  }
}

// ---------------- MFMA GEMM, m97 structure: 128x128 tile, global_load_lds, swizzled LDS ----------------
__global__ __launch_bounds__(256) void k_mm(const f16* __restrict__ xh, const f16* __restrict__ Wh,
                                            f16* __restrict__ xq) {
  __shared__ __align__(16) f16 As[128 * 32];
  __shared__ __align__(16) f16 Bs[128 * 32];
  int m0 = blockIdx.x * 128, n0 = blockIdx.y * 128;
  int tid = threadIdx.x, wv = tid >> 6, lane = tid & 63;
  int wr = wv >> 1, wc = wv & 1;

  int r0a = 32 * wv + (lane >> 2);
  int ca  = ((lane & 3) ^ ((r0a >> 1) & 3)) * 8;
  int r0b = r0a + 16;
  int cb  = ((lane & 3) ^ ((r0b >> 1) & 3)) * 8;

  f32x4 acc[4][4] = {};
  for (int ks = 0; ks < KP / 32; ++ks) {
    __syncthreads();
    GLDS16(xh + (size_t)(m0 + r0a) * KP + ks * 32 + ca, As + (32 * wv) * 32);
    GLDS16(xh + (size_t)(m0 + r0b) * KP + ks * 32 + cb, As + (32 * wv + 16) * 32);
    GLDS16(Wh + (size_t)(n0 + r0a) * KP + ks * 32 + ca, Bs + (32 * wv) * 32);
    GLDS16(Wh + (size_t)(n0 + r0b) * KP + ks * 32 + cb, Bs + (32 * wv + 16) * 32);
    __syncthreads();

    f16x8 af[4], bf[4];
#pragma unroll
    for (int i = 0; i < 4; ++i) {
      int rA = wr * 64 + i * 16 + (lane & 15);
      int sA = (lane >> 4) ^ ((rA >> 1) & 3);
      af[i] = *(const f16x8*)&As[rA * 32 + sA * 8];
      int rB = wc * 64 + i * 16 + (lane & 15);
      int sB = (lane >> 4) ^ ((rB >> 1) & 3);
      bf[i] = *(const f16x8*)&Bs[rB * 32 + sB * 8];
    }
#pragma unroll
    for (int i = 0; i < 4; ++i)
#pragma unroll
      for (int j = 0; j < 4; ++j)
        acc[i][j] = __builtin_amdgcn_mfma_f32_16x16x32_f16(af[i], bf[j], acc[i][j], 0, 0, 0);
  }

#pragma unroll
  for (int i = 0; i < 4; ++i) {
#pragma unroll
    for (int j = 0; j < 4; ++j) {
      int col = n0 + wc * 64 + j * 16 + (lane & 15);
      if (col < Cc) {
        int rbase = m0 + wr * 64 + i * 16 + ((lane >> 4) * 4);
#pragma unroll
        for (int r = 0; r < 4; ++r) {
          int row = rbase + r;
          if (row < Nn) xq[(size_t)row * SQ + col] = (f16)acc[i][j][r];
        }
      }
    }
  }
}

// ---------------- single-block scan + degree-balanced permutation ----------------
__global__ __launch_bounds__(1024) void k_scan(const int* __restrict__ cnt,
                                               int* __restrict__ offs, int* __restrict__ cur,
                                               int* __restrict__ perm) {
  __shared__ int wsum[16];
  __shared__ int dhist[64];
  __shared__ int dcur[64];
  int t = threadIdx.x, wv = t >> 6, ln = t & 63;
  int i0 = t * 20;
  int v[20];
  int tot = 0;
  if (i0 < Nn) {
    const int4* p = (const int4*)(cnt + i0);
#pragma unroll
    for (int q = 0; q < 5; ++q) {
      int4 w = p[q];
      v[4 * q] = w.x; v[4 * q + 1] = w.y; v[4 * q + 2] = w.z; v[4 * q + 3] = w.w;
    }
#pragma unroll
    for (int j = 0; j < 20; ++j) tot += v[j];
  }
  if (t < 64) dhist[t] = 0;
  int s = tot;
  for (int o = 1; o < 64; o <<= 1) {
    int u = __shfl_up(s, o, 64);
    if (ln >= o) s += u;
  }
  if (ln == 63) wsum[wv] = s;
  __syncthreads();  // dhist zeroed + wsum written
  if (i0 < Nn) {
#pragma unroll
    for (int j = 0; j < 20; ++j) atomicAdd(&dhist[min(v[j], 63)], 1);
  }
  if (wv == 0) {
    int w = (ln < 16) ? wsum[ln] : 0;
    for (int o = 1; o < 16; o <<= 1) {
      int u = __shfl_up(w, o, 64);
      if (ln >= o) w += u;
    }
    if (ln < 16) wsum[ln] = w;
  }
  __syncthreads();  // dhist complete, wsum scanned
  if (wv == 0) {    // exclusive scan of 64 degree bins
    int h = dhist[ln];
    int sc = h;
    for (int o = 1; o < 64; o <<= 1) {
      int u = __shfl_up(sc, o, 64);
      if (ln >= o) sc += u;
    }
    dcur[ln] = sc - h;
  }
  __syncthreads();  // dcur ready
  if (i0 < Nn) {
    int run = (wv > 0 ? wsum[wv - 1] : 0) + (s - tot);
#pragma unroll
    for (int j = 0; j < 20; ++j) {
      offs[i0 + j] = run;
      cur[i0 + j] = run;
      run += v[j];
      int pos = atomicAdd(&dcur[min(v[j], 63)], 1);
      perm[pos] = i0 + j;
    }
  }
  if (t == 0) offs[Nn] = wsum[15];
}

// ---------------- scatter: sorted edge records {src, e0, e1} ----------------
__global__ void k_scatter(const int* __restrict__ ei,
                          const float* __restrict__ a_src, const float* __restrict__ a_dst,
                          int* __restrict__ cur, float4* __restrict__ erec) {
  int e = blockIdx.x * 256 + threadIdx.x;
  if (e < Ee) {
    int s = ei[e], d = ei[Ee + e];
    float2 av = *(const float2*)(a_src + 2 * s);
    float2 bv = *(const float2*)(a_dst + 2 * d);
    float e0 = __expf(lrelu(av.x + bv.x));
    float e1 = __expf(lrelu(av.y + bv.y));
    int pos = atomicAdd(&cur[d], 1);
    erec[pos] = make_float4(__int_as_float(s), e0, e1, 0.f);
  }
}

// ---------------- wave-per-node (degree-balanced): gather-FMA aggregation + epilogue ----------------
__global__ __launch_bounds__(256) void k_agg(const f16* __restrict__ xq,
    const float4* __restrict__ erec, const int* __restrict__ perm,
    const float* __restrict__ a_src, const float* __restrict__ a_dst,
    const int* __restrict__ offs,
    const float* __restrict__ bias, const float* __restrict__ lin_w,
    const float* __restrict__ lin_b, float* __restrict__ out) {
  __shared__ float sAgg[4][600];
  int tid = threadIdx.x, wv = tid >> 6, ln = tid & 63;
  int n = perm[blockIdx.x * 4 + wv];
  int beg = offs[n], deg = offs[n + 1] - beg;
  float2 adv = *(const float2*)(a_dst + 2 * n);
  float2 asv = *(const float2*)(a_src + 2 * n);
  float sw0 = __expf(lrelu(asv.x + adv.x));
  float sw1 = __expf(lrelu(asv.y + adv.y));

  // denominators from erec (coalesced strided pass + butterfly)
  float t0 = 0.f, t1 = 0.f;
  for (int i = ln; i < deg; i += 64) {
    float4 r = erec[beg + i];
    t0 += r.y; t1 += r.z;
  }
  for (int o = 32; o > 0; o >>= 1) {
    t0 += __shfl_xor(t0, o, 64);
    t1 += __shfl_xor(t1, o, 64);
  }
  float inv0 = 1.f / (t0 + sw0), inv1 = 1.f / (t1 + sw1);

  float acc[12] = {};
  auto addrow = [&](const f16* row, float p0, float p1) {
#pragma unroll
    for (int k = 0; k < 3; ++k) {
      int c = 4 * ln + 256 * k;  // head split at 300 is 4-aligned
      if (c < Cc) {
        f16x4 hv = *(const f16x4*)(row + c);
        float p = (c < Dd) ? p0 : p1;
        acc[4 * k + 0] += p * (float)hv[0];
        acc[4 * k + 1] += p * (float)hv[1];
        acc[4 * k + 2] += p * (float)hv[2];
        acc[4 * k + 3] += p * (float)hv[3];
      }
    }
  };

  int j = 0;
  for (; j + 4 <= deg; j += 4) {  // wave-uniform 16B broadcast loads, 4 rows in flight
    float4 r0 = erec[beg + j + 0];
    float4 r1 = erec[beg + j + 1];
    float4 r2 = erec[beg + j + 2];
    float4 r3 = erec[beg + j + 3];
    addrow(xq + (size_t)__float_as_int(r0.x) * SQ, r0.y * inv0, r0.z * inv1);
    addrow(xq + (size_t)__float_as_int(r1.x) * SQ, r1.y * inv0, r1.z * inv1);
    addrow(xq + (size_t)__float_as_int(r2.x) * SQ, r2.y * inv0, r2.z * inv1);
    addrow(xq + (size_t)__float_as_int(r3.x) * SQ, r3.y * inv0, r3.z * inv1);
  }
  for (; j < deg; ++j) {
    float4 r = erec[beg + j];
    addrow(xq + (size_t)__float_as_int(r.x) * SQ, r.y * inv0, r.z * inv1);
  }
  addrow(xq + (size_t)n * SQ, sw0 * inv0, sw1 * inv1);  // self-loop

#pragma unroll
  for (int k = 0; k < 3; ++k) {
    int c = 4 * ln + 256 * k;
    if (c < Cc) {
#pragma unroll
      for (int q = 0; q < 4; ++q) sAgg[wv][c + q] = acc[4 * k + q];
    }
  }
  __syncthreads();

  float part = 0.f;
#pragma unroll
  for (int k = 0; k < 5; ++k) {
    int d = ln + 64 * k;
    if (d < Dd) {
      float v = 0.5f * (sAgg[wv][d] + sAgg[wv][d + Dd]) + bias[d];
      v = fmaxf(v, 0.f);
      part += v * lin_w[d];
    }
  }
  for (int o = 32; o > 0; o >>= 1) part += __shfl_xor(part, o, 64);
  if (ln == 0) out[n] = part + lin_b[0];
}

extern "C" void kernel_launch(void* const* d_in, const int* in_sizes, int n_in,
                              void* d_out, int out_size, void* d_ws, size_t ws_size,
                              hipStream_t stream) {
  const float* x       = (const float*)d_in[0];
  const int*   ei      = (const int*)d_in[1];
  const float* W       = (const float*)d_in[2];
  const float* att_src = (const float*)d_in[3];
  const float* att_dst = (const float*)d_in[4];
  const float* bias    = (const float*)d_in[5];
  const float* lin_w   = (const float*)d_in[6];
  const float* lin_b   = (const float*)d_in[7];
  float* out = (float*)d_out;

  char* ws = (char*)d_ws;
  size_t off = 0;
  auto alloc = [&](size_t bytes) {
    void* p = ws + off;
    off = (off + bytes + 255) & ~(size_t)255;
    return p;
  };
  f16*    xq    = (f16*)alloc((size_t)Nn * SQ * 2);
  f16*    xh    = (f16*)alloc((size_t)MP * KP * 2);
  f16*    Wh    = (f16*)alloc((size_t)NP * KP * 2);
  float*  vatt  = (float*)alloc((size_t)Dd * 4 * 4);
  float*  a_src = (float*)alloc((size_t)Nn * Hh * 4);
  float*  a_dst = (float*)alloc((size_t)Nn * Hh * 4);
  int*    cnt   = (int*)alloc((size_t)Nn * 4);
  int*    offs  = (int*)alloc((size_t)(Nn + 1) * 4);
  int*    cur   = (int*)alloc((size_t)Nn * 4);
  int*    perm  = (int*)alloc((size_t)Nn * 4);
  float4* erec  = (float4*)alloc((size_t)Ee * 16);

  k_pre2<<<NP * (KP / 4) / 256, 256, 0, stream>>>(W, att_src, att_dst, Wh, vatt, cnt);
  k_pre1<<<MP / 4, 256, 0, stream>>>(x, vatt, ei, xh, a_src, a_dst, cnt);
  k_mm<<<dim3(MP / 128, NP / 128), 256, 0, stream>>>(xh, Wh, xq);
  k_scan<<<1, 1024, 0, stream>>>(cnt, offs, cur, perm);
  k_scatter<<<(Ee + 255) / 256, 256, 0, stream>>>(ei, a_src, a_dst, cur, erec);
  k_agg<<<Nn / 4, 256, 0, stream>>>(xq, erec, perm, a_src, a_dst, offs, bias, lin_w, lin_b, out);
}

// Round 11
// 208.842 us; speedup vs baseline: 1.1818x; 1.0651x over previous
//
#include <hip/hip_runtime.h>
#include <math.h>
#include <string.h>

#define Nn 20000
#define Ee 320000
#define Dd 300
#define Hh 2
#define Cc 600    // Hh*Dd
#define KP 320    // K padded to multiple of 32
#define MP 20096  // M padded to 157*128
#define NP 640    // N padded to 5*128
#define SQ 640    // xq row stride (elems): 1280 B, 16B-aligned rows
#define MMB 785   // (MP/128)*(NP/128) mm blocks in fused kernel

typedef _Float16 f16;
typedef __attribute__((ext_vector_type(8))) _Float16 f16x8;
typedef __attribute__((ext_vector_type(4))) _Float16 f16x4;
typedef __attribute__((ext_vector_type(4))) float f32x4;

__device__ __forceinline__ float lrelu(float x) { return x > 0.f ? x : 0.2f * x; }

#define GLDS16(src, dst)                                                            \
  __builtin_amdgcn_global_load_lds(                                                 \
      (const __attribute__((address_space(1))) unsigned int*)(src),                 \
      (__attribute__((address_space(3))) unsigned int*)(dst), 16, 0, 0)

// ---------------- k_pre2: Wh (transposed fp16) + vatt + zero cnt ----------------
__global__ __launch_bounds__(256) void k_pre2(const float* __restrict__ W,
                                              const float* __restrict__ att_src,
                                              const float* __restrict__ att_dst,
                                              f16* __restrict__ Wh, float* __restrict__ vatt,
                                              int* __restrict__ cnt) {
  int idx = blockIdx.x * 256 + threadIdx.x;  // grid: NP*KP/4 = 51200 threads
  if (idx < Nn) cnt[idx] = 0;
  {
    int c = idx % NP, k0 = (idx / NP) * 4;
    f16x4 h;
#pragma unroll
    for (int j = 0; j < 4; ++j) {
      int k = k0 + j;
      h[j] = (f16)((k < Dd && c < Cc) ? W[(size_t)k * Cc + c] : 0.f);
    }
    *(f16x4*)(Wh + (size_t)c * KP + k0) = h;
  }
  int wid = idx >> 6, ln = idx & 63;
  if (wid < Dd) {
    float s0 = 0.f, s1 = 0.f, t0 = 0.f, t1 = 0.f;
    for (int e = ln; e < Dd; e += 64) {
      float w0 = W[(size_t)wid * Cc + e];
      float w1 = W[(size_t)wid * Cc + Dd + e];
      s0 += w0 * att_src[e];  s1 += w1 * att_src[Dd + e];
      t0 += w0 * att_dst[e];  t1 += w1 * att_dst[Dd + e];
    }
    for (int o = 32; o > 0; o >>= 1) {
      s0 += __shfl_down(s0, o, 64); s1 += __shfl_down(s1, o, 64);
      t0 += __shfl_down(t0, o, 64); t1 += __shfl_down(t1, o, 64);
    }
    if (ln == 0) {
      vatt[wid * 4 + 0] = s0; vatt[wid * 4 + 1] = s1;
      vatt[wid * 4 + 2] = t0; vatt[wid * 4 + 3] = t1;
    }
  }
}

// ---------------- k_pre1: xh (fp16, padded) + logits + edge histogram ----------------
__global__ __launch_bounds__(256) void k_pre1(const float* __restrict__ x,
                                              const float* __restrict__ vatt,
                                              const int* __restrict__ ei,
                                              f16* __restrict__ xh,
                                              float* __restrict__ a_src, float* __restrict__ a_dst,
                                              int* __restrict__ cnt) {
  int gid = blockIdx.x * 256 + threadIdx.x;  // 5024*256 = 1,286,144 >= Ee
  if (gid < Ee) atomicAdd(&cnt[ei[Ee + gid]], 1);
  int wv = threadIdx.x >> 6, ln = threadIdx.x & 63;
  int n = blockIdx.x * 4 + wv;
  if (n >= MP) return;
  if (n >= Nn) {  // zero-fill pad rows for k_mm
#pragma unroll
    for (int k = 0; k < 5; ++k) xh[(size_t)n * KP + ln + 64 * k] = (f16)0.f;
    return;
  }
  const float* xr = x + (size_t)n * Dd;
  float s0 = 0.f, s1 = 0.f, t0 = 0.f, t1 = 0.f;
#pragma unroll
  for (int k = 0; k < 5; ++k) {
    int d = ln + 64 * k;  // 0..319
    float xv = 0.f;
    if (d < Dd) {
      xv = xr[d];
      float4 vv = *(const float4*)(vatt + d * 4);
      s0 += xv * vv.x; s1 += xv * vv.y; t0 += xv * vv.z; t1 += xv * vv.w;
    }
    xh[(size_t)n * KP + d] = (f16)xv;
  }
  for (int o = 32; o > 0; o >>= 1) {
    s0 += __shfl_down(s0, o, 64); s1 += __shfl_down(s1, o, 64);
    t0 += __shfl_down(t0, o, 64); t1 += __shfl_down(t1, o, 64);
  }
  if (ln == 0) {
    a_src[n * 2 + 0] = s0; a_src[n * 2 + 1] = s1;
    a_dst[n * 2 + 0] = t0; a_dst[n * 2 + 1] = t1;
  }
}

// ---------------- single-block scan: offs + cur ----------------
__global__ __launch_bounds__(1024) void k_scan(const int* __restrict__ cnt,
                                               int* __restrict__ offs, int* __restrict__ cur) {
  __shared__ int wsum[16];
  int t = threadIdx.x, wv = t >> 6, ln = t & 63;
  int i0 = t * 20;
  int v[20];
  int tot = 0;
  if (i0 < Nn) {
    const int4* p = (const int4*)(cnt + i0);
#pragma unroll
    for (int q = 0; q < 5; ++q) {
      int4 w = p[q];
      v[4 * q] = w.x; v[4 * q + 1] = w.y; v[4 * q + 2] = w.z; v[4 * q + 3] = w.w;
    }
#pragma unroll
    for (int j = 0; j < 20; ++j) tot += v[j];
  }
  int s = tot;
  for (int o = 1; o < 64; o <<= 1) {
    int u = __shfl_up(s, o, 64);
    if (ln >= o) s += u;
  }
  if (ln == 63) wsum[wv] = s;
  __syncthreads();
  if (wv == 0) {
    int w = (ln < 16) ? wsum[ln] : 0;
    for (int o = 1; o < 16; o <<= 1) {
      int u = __shfl_up(w, o, 64);
      if (ln >= o) w += u;
    }
    if (ln < 16) wsum[ln] = w;
  }
  __syncthreads();
  if (i0 < Nn) {
    int run = (wv > 0 ? wsum[wv - 1] : 0) + (s - tot);
#pragma unroll
    for (int j = 0; j < 20; ++j) {
      offs[i0 + j] = run;
      cur[i0 + j] = run;
      run += v[j];
    }
  }
  if (t == 0) offs[Nn] = wsum[15];
}

// ---------------- fused: MFMA GEMM tiles (blocks 0..784) + edge scatter (rest) ----------------
__global__ __launch_bounds__(256) void k_mid(const f16* __restrict__ xh, const f16* __restrict__ Wh,
                                             f16* __restrict__ xq,
                                             const int* __restrict__ ei,
                                             const float* __restrict__ a_src,
                                             const float* __restrict__ a_dst,
                                             int* __restrict__ cur, uint2* __restrict__ erec) {
  __shared__ __align__(16) f16 As[128 * 32];
  __shared__ __align__(16) f16 Bs[128 * 32];
  int bid = blockIdx.x, tid = threadIdx.x;

  if (bid >= MMB) {  // ---- scatter role ----
    int e = (bid - MMB) * 256 + tid;
    if (e < Ee) {
      int s = ei[e], d = ei[Ee + e];
      float2 av = *(const float2*)(a_src + 2 * s);
      float2 bv = *(const float2*)(a_dst + 2 * d);
      f16 h0 = (f16)__expf(lrelu(av.x + bv.x));
      f16 h1 = (f16)__expf(lrelu(av.y + bv.y));
      unsigned short u0, u1;
      __builtin_memcpy(&u0, &h0, 2);
      __builtin_memcpy(&u1, &h1, 2);
      int pos = atomicAdd(&cur[d], 1);
      erec[pos] = make_uint2((unsigned)s, ((unsigned)u1 << 16) | u0);
    }
    return;
  }

  // ---- mm role ----
  int m0 = (bid % 157) * 128, n0 = (bid / 157) * 128;
  int wv = tid >> 6, lane = tid & 63;
  int wr = wv >> 1, wc = wv & 1;

  int r0a = 32 * wv + (lane >> 2);
  int ca  = ((lane & 3) ^ ((r0a >> 1) & 3)) * 8;
  int r0b = r0a + 16;
  int cb  = ((lane & 3) ^ ((r0b >> 1) & 3)) * 8;

  f32x4 acc[4][4] = {};
  for (int ks = 0; ks < KP / 32; ++ks) {
    __syncthreads();
    GLDS16(xh + (size_t)(m0 + r0a) * KP + ks * 32 + ca, As + (32 * wv) * 32);
    GLDS16(xh + (size_t)(m0 + r0b) * KP + ks * 32 + cb, As + (32 * wv + 16) * 32);
    GLDS16(Wh + (size_t)(n0 + r0a) * KP + ks * 32 + ca, Bs + (32 * wv) * 32);
    GLDS16(Wh + (size_t)(n0 + r0b) * KP + ks * 32 + cb, Bs + (32 * wv + 16) * 32);
    __syncthreads();

    f16x8 af[4], bf[4];
#pragma unroll
    for (int i = 0; i < 4; ++i) {
      int rA = wr * 64 + i * 16 + (lane & 15);
      int sA = (lane >> 4) ^ ((rA >> 1) & 3);
      af[i] = *(const f16x8*)&As[rA * 32 + sA * 8];
      int rB = wc * 64 + i * 16 + (lane & 15);
      int sB = (lane >> 4) ^ ((rB >> 1) & 3);
      bf[i] = *(const f16x8*)&Bs[rB * 32 + sB * 8];
    }
#pragma unroll
    for (int i = 0; i < 4; ++i)
#pragma unroll
      for (int j = 0; j < 4; ++j)
        acc[i][j] = __builtin_amdgcn_mfma_f32_16x16x32_f16(af[i], bf[j], acc[i][j], 0, 0, 0);
  }

#pragma unroll
  for (int i = 0; i < 4; ++i) {
#pragma unroll
    for (int j = 0; j < 4; ++j) {
      int col = n0 + wc * 64 + j * 16 + (lane & 15);
      if (col < Cc) {
        int rbase = m0 + wr * 64 + i * 16 + ((lane >> 4) * 4);
#pragma unroll
        for (int r = 0; r < 4; ++r) {
          int row = rbase + r;
          if (row < Nn) xq[(size_t)row * SQ + col] = (f16)acc[i][j][r];
        }
      }
    }
  }
}

// ---------------- wave-per-node: single-pass unnormalized gather-FMA + fused normalize ----------------
__global__ __launch_bounds__(256) void k_agg(const f16* __restrict__ xq,
    const uint2* __restrict__ erec,
    const float* __restrict__ a_src, const float* __restrict__ a_dst,
    const int* __restrict__ offs,
    const float* __restrict__ bias, const float* __restrict__ lin_w,
    const float* __restrict__ lin_b, float* __restrict__ out) {
  __shared__ float sAgg[4][600];
  int tid = threadIdx.x, wv = tid >> 6, ln = tid & 63;
  int n = blockIdx.x * 4 + wv;
  int beg = offs[n], deg = offs[n + 1] - beg;
  float2 adv = *(const float2*)(a_dst + 2 * n);
  float2 asv = *(const float2*)(a_src + 2 * n);
  float sw0 = __expf(lrelu(asv.x + adv.x));
  float sw1 = __expf(lrelu(asv.y + adv.y));

  float acc[12] = {};
  float t0 = 0.f, t1 = 0.f;  // denominators, accumulated redundantly on all lanes
  auto unpack = [](unsigned w, float& e0, float& e1) {
    unsigned short q0 = (unsigned short)(w & 0xffff), q1 = (unsigned short)(w >> 16);
    f16 h0, h1;
    __builtin_memcpy(&h0, &q0, 2);
    __builtin_memcpy(&h1, &q1, 2);
    e0 = (float)h0; e1 = (float)h1;
  };
  auto addrow = [&](const f16* row, float p0, float p1) {
#pragma unroll
    for (int k = 0; k < 3; ++k) {
      int c = 4 * ln + 256 * k;  // head split at 300 is 4-aligned
      if (c < Cc) {
        f16x4 hv = *(const f16x4*)(row + c);
        float p = (c < Dd) ? p0 : p1;
        acc[4 * k + 0] += p * (float)hv[0];
        acc[4 * k + 1] += p * (float)hv[1];
        acc[4 * k + 2] += p * (float)hv[2];
        acc[4 * k + 3] += p * (float)hv[3];
      }
    }
  };

  int j = 0;
  for (; j + 4 <= deg; j += 4) {  // wave-uniform 8B broadcast loads, 4 rows in flight
    uint2 r0 = erec[beg + j + 0];
    uint2 r1 = erec[beg + j + 1];
    uint2 r2 = erec[beg + j + 2];
    uint2 r3 = erec[beg + j + 3];
    float e00, e01, e10, e11, e20, e21, e30, e31;
    unpack(r0.y, e00, e01); unpack(r1.y, e10, e11);
    unpack(r2.y, e20, e21); unpack(r3.y, e30, e31);
    t0 += e00 + e10 + e20 + e30;
    t1 += e01 + e11 + e21 + e31;
    addrow(xq + (size_t)r0.x * SQ, e00, e01);
    addrow(xq + (size_t)r1.x * SQ, e10, e11);
    addrow(xq + (size_t)r2.x * SQ, e20, e21);
    addrow(xq + (size_t)r3.x * SQ, e30, e31);
  }
  for (; j < deg; ++j) {
    uint2 r = erec[beg + j];
    float e0, e1;
    unpack(r.y, e0, e1);
    t0 += e0; t1 += e1;
    addrow(xq + (size_t)r.x * SQ, e0, e1);
  }
  addrow(xq + (size_t)n * SQ, sw0, sw1);  // self-loop (unnormalized)

  float inv0 = 1.f / (t0 + sw0), inv1 = 1.f / (t1 + sw1);
#pragma unroll
  for (int k = 0; k < 3; ++k) {
    int c = 4 * ln + 256 * k;
    if (c < Cc) {
      float p = (c < Dd) ? inv0 : inv1;
#pragma unroll
      for (int q = 0; q < 4; ++q) sAgg[wv][c + q] = acc[4 * k + q] * p;
    }
  }
  __syncthreads();

  float part = 0.f;
#pragma unroll
  for (int k = 0; k < 5; ++k) {
    int d = ln + 64 * k;
    if (d < Dd) {
      float v = 0.5f * (sAgg[wv][d] + sAgg[wv][d + Dd]) + bias[d];
      v = fmaxf(v, 0.f);
      part += v * lin_w[d];
    }
  }
  for (int o = 32; o > 0; o >>= 1) part += __shfl_xor(part, o, 64);
  if (ln == 0) out[n] = part + lin_b[0];
}

extern "C" void kernel_launch(void* const* d_in, const int* in_sizes, int n_in,
                              void* d_out, int out_size, void* d_ws, size_t ws_size,
                              hipStream_t stream) {
  const float* x       = (const float*)d_in[0];
  const int*   ei      = (const int*)d_in[1];
  const float* W       = (const float*)d_in[2];
  const float* att_src = (const float*)d_in[3];
  const float* att_dst = (const float*)d_in[4];
  const float* bias    = (const float*)d_in[5];
  const float* lin_w   = (const float*)d_in[6];
  const float* lin_b   = (const float*)d_in[7];
  float* out = (float*)d_out;

  char* ws = (char*)d_ws;
  size_t off = 0;
  auto alloc = [&](size_t bytes) {
    void* p = ws + off;
    off = (off + bytes + 255) & ~(size_t)255;
    return p;
  };
  f16*   xq    = (f16*)alloc((size_t)Nn * SQ * 2);
  f16*   xh    = (f16*)alloc((size_t)MP * KP * 2);
  f16*   Wh    = (f16*)alloc((size_t)NP * KP * 2);
  float* vatt  = (float*)alloc((size_t)Dd * 4 * 4);
  float* a_src = (float*)alloc((size_t)Nn * Hh * 4);
  float* a_dst = (float*)alloc((size_t)Nn * Hh * 4);
  int*   cnt   = (int*)alloc((size_t)Nn * 4);
  int*   offs  = (int*)alloc((size_t)(Nn + 1) * 4);
  int*   cur   = (int*)alloc((size_t)Nn * 4);
  uint2* erec  = (uint2*)alloc((size_t)Ee * 8);

  k_pre2<<<NP * (KP / 4) / 256, 256, 0, stream>>>(W, att_src, att_dst, Wh, vatt, cnt);
  k_pre1<<<MP / 4, 256, 0, stream>>>(x, vatt, ei, xh, a_src, a_dst, cnt);
  k_scan<<<1, 1024, 0, stream>>>(cnt, offs, cur);
  k_mid<<<MMB + (Ee + 255) / 256, 256, 0, stream>>>(xh, Wh, xq, ei, a_src, a_dst, cur, erec);
  k_agg<<<Nn / 4, 256, 0, stream>>>(xq, erec, a_src, a_dst, offs, bias, lin_w, lin_b, out);
}

// Round 13
// 199.222 us; speedup vs baseline: 1.2388x; 1.0483x over previous
//
#include <hip/hip_runtime.h>
#include <math.h>
#include <string.h>

#define Nn 20000
#define Ee 320000
#define Dd 300
#define Hh 2
#define Cc 600    // Hh*Dd
#define KP 320    // K padded to multiple of 32
#define MP 20096  // M padded to 157*128
#define NP 640    // N padded to 5*128
#define SQ 640    // xq row stride (elems): 1280 B, 16B-aligned rows
#define MMB 785   // (MP/128)*(NP/128) mm blocks in fused kernel

typedef _Float16 f16;
typedef __attribute__((ext_vector_type(8))) _Float16 f16x8;
typedef __attribute__((ext_vector_type(4))) _Float16 f16x4;
typedef __attribute__((ext_vector_type(4))) float f32x4;

__device__ __forceinline__ float lrelu(float x) { return x > 0.f ? x : 0.2f * x; }

#define GLDS16(src, dst)                                                            \
  __builtin_amdgcn_global_load_lds(                                                 \
      (const __attribute__((address_space(1))) unsigned int*)(src),                 \
      (__attribute__((address_space(3))) unsigned int*)(dst), 16, 0, 0)

// ---------------- k_pre2: Wh (transposed fp16) + vatt + zero cnt ----------------
__global__ __launch_bounds__(256) void k_pre2(const float* __restrict__ W,
                                              const float* __restrict__ att_src,
                                              const float* __restrict__ att_dst,
                                              f16* __restrict__ Wh, float* __restrict__ vatt,
                                              int* __restrict__ cnt) {
  int idx = blockIdx.x * 256 + threadIdx.x;  // grid: NP*KP/4 = 51200 threads
  if (idx < Nn) cnt[idx] = 0;
  {
    int c = idx % NP, k0 = (idx / NP) * 4;
    f16x4 h;
#pragma unroll
    for (int j = 0; j < 4; ++j) {
      int k = k0 + j;
      h[j] = (f16)((k < Dd && c < Cc) ? W[(size_t)k * Cc + c] : 0.f);
    }
    *(f16x4*)(Wh + (size_t)c * KP + k0) = h;
  }
  int wid = idx >> 6, ln = idx & 63;
  if (wid < Dd) {
    float s0 = 0.f, s1 = 0.f, t0 = 0.f, t1 = 0.f;
    for (int e = ln; e < Dd; e += 64) {
      float w0 = W[(size_t)wid * Cc + e];
      float w1 = W[(size_t)wid * Cc + Dd + e];
      s0 += w0 * att_src[e];  s1 += w1 * att_src[Dd + e];
      t0 += w0 * att_dst[e];  t1 += w1 * att_dst[Dd + e];
    }
    for (int o = 32; o > 0; o >>= 1) {
      s0 += __shfl_down(s0, o, 64); s1 += __shfl_down(s1, o, 64);
      t0 += __shfl_down(t0, o, 64); t1 += __shfl_down(t1, o, 64);
    }
    if (ln == 0) {
      vatt[wid * 4 + 0] = s0; vatt[wid * 4 + 1] = s1;
      vatt[wid * 4 + 2] = t0; vatt[wid * 4 + 3] = t1;
    }
  }
}

// ---------------- k_pre1: xh (fp16, padded) + logits + edge histogram with rank ----------------
__global__ __launch_bounds__(256) void k_pre1(const float* __restrict__ x,
                                              const float* __restrict__ vatt,
                                              const int* __restrict__ ei,
                                              f16* __restrict__ xh,
                                              float* __restrict__ a_src, float* __restrict__ a_dst,
                                              int* __restrict__ cnt,
                                              unsigned short* __restrict__ rk) {
  int gid = blockIdx.x * 256 + threadIdx.x;  // 5024*256 = 1,286,144 >= Ee
  if (gid < Ee) rk[gid] = (unsigned short)atomicAdd(&cnt[ei[Ee + gid]], 1);
  int wv = threadIdx.x >> 6, ln = threadIdx.x & 63;
  int n = blockIdx.x * 4 + wv;
  if (n >= MP) return;
  if (n >= Nn) {  // zero-fill pad rows for k_mm
#pragma unroll
    for (int k = 0; k < 5; ++k) xh[(size_t)n * KP + ln + 64 * k] = (f16)0.f;
    return;
  }
  const float* xr = x + (size_t)n * Dd;
  float s0 = 0.f, s1 = 0.f, t0 = 0.f, t1 = 0.f;
#pragma unroll
  for (int k = 0; k < 5; ++k) {
    int d = ln + 64 * k;  // 0..319
    float xv = 0.f;
    if (d < Dd) {
      xv = xr[d];
      float4 vv = *(const float4*)(vatt + d * 4);
      s0 += xv * vv.x; s1 += xv * vv.y; t0 += xv * vv.z; t1 += xv * vv.w;
    }
    xh[(size_t)n * KP + d] = (f16)xv;
  }
  for (int o = 32; o > 0; o >>= 1) {
    s0 += __shfl_down(s0, o, 64); s1 += __shfl_down(s1, o, 64);
    t0 += __shfl_down(t0, o, 64); t1 += __shfl_down(t1, o, 64);
  }
  if (ln == 0) {
    a_src[n * 2 + 0] = s0; a_src[n * 2 + 1] = s1;
    a_dst[n * 2 + 0] = t0; a_dst[n * 2 + 1] = t1;
  }
}

// ---------------- single-block scan: offs only ----------------
__global__ __launch_bounds__(1024) void k_scan(const int* __restrict__ cnt,
                                               int* __restrict__ offs) {
  __shared__ int wsum[16];
  int t = threadIdx.x, wv = t >> 6, ln = t & 63;
  int i0 = t * 20;
  int v[20];
  int tot = 0;
  if (i0 < Nn) {
    const int4* p = (const int4*)(cnt + i0);
#pragma unroll
    for (int q = 0; q < 5; ++q) {
      int4 w = p[q];
      v[4 * q] = w.x; v[4 * q + 1] = w.y; v[4 * q + 2] = w.z; v[4 * q + 3] = w.w;
    }
#pragma unroll
    for (int j = 0; j < 20; ++j) tot += v[j];
  }
  int s = tot;
  for (int o = 1; o < 64; o <<= 1) {
    int u = __shfl_up(s, o, 64);
    if (ln >= o) s += u;
  }
  if (ln == 63) wsum[wv] = s;
  __syncthreads();
  if (wv == 0) {
    int w = (ln < 16) ? wsum[ln] : 0;
    for (int o = 1; o < 16; o <<= 1) {
      int u = __shfl_up(w, o, 64);
      if (ln >= o) w += u;
    }
    if (ln < 16) wsum[ln] = w;
  }
  __syncthreads();
  if (i0 < Nn) {
    int run = (wv > 0 ? wsum[wv - 1] : 0) + (s - tot);
#pragma unroll
    for (int j = 0; j < 20; ++j) {
      offs[i0 + j] = run;
      run += v[j];
    }
  }
  if (t == 0) offs[Nn] = wsum[15];
}

// ---------------- fused: MFMA GEMM tiles (blocks 0..784) + atomic-free edge scatter ----------------
__global__ __launch_bounds__(256) void k_mid(const f16* __restrict__ xh, const f16* __restrict__ Wh,
                                             f16* __restrict__ xq,
                                             const int* __restrict__ ei,
                                             const float* __restrict__ a_src,
                                             const float* __restrict__ a_dst,
                                             const int* __restrict__ offs,
                                             const unsigned short* __restrict__ rk,
                                             uint2* __restrict__ erec) {
  __shared__ __align__(16) f16 As[128 * 32];
  __shared__ __align__(16) f16 Bs[128 * 32];
  int bid = blockIdx.x, tid = threadIdx.x;

  if (bid >= MMB) {  // ---- scatter role (no atomics) ----
    int e = (bid - MMB) * 256 + tid;
    if (e < Ee) {
      int s = ei[e], d = ei[Ee + e];
      float2 av = *(const float2*)(a_src + 2 * s);
      float2 bv = *(const float2*)(a_dst + 2 * d);
      f16 h0 = (f16)__expf(lrelu(av.x + bv.x));
      f16 h1 = (f16)__expf(lrelu(av.y + bv.y));
      unsigned short u0, u1;
      __builtin_memcpy(&u0, &h0, 2);
      __builtin_memcpy(&u1, &h1, 2);
      int pos = offs[d] + (int)rk[e];
      erec[pos] = make_uint2((unsigned)s, ((unsigned)u1 << 16) | u0);
    }
    return;
  }

  // ---- mm role ----
  int m0 = (bid % 157) * 128, n0 = (bid / 157) * 128;
  int wv = tid >> 6, lane = tid & 63;
  int wr = wv >> 1, wc = wv & 1;

  int r0a = 32 * wv + (lane >> 2);
  int ca  = ((lane & 3) ^ ((r0a >> 1) & 3)) * 8;
  int r0b = r0a + 16;
  int cb  = ((lane & 3) ^ ((r0b >> 1) & 3)) * 8;

  f32x4 acc[4][4] = {};
  for (int ks = 0; ks < KP / 32; ++ks) {
    __syncthreads();
    GLDS16(xh + (size_t)(m0 + r0a) * KP + ks * 32 + ca, As + (32 * wv) * 32);
    GLDS16(xh + (size_t)(m0 + r0b) * KP + ks * 32 + cb, As + (32 * wv + 16) * 32);
    GLDS16(Wh + (size_t)(n0 + r0a) * KP + ks * 32 + ca, Bs + (32 * wv) * 32);
    GLDS16(Wh + (size_t)(n0 + r0b) * KP + ks * 32 + cb, Bs + (32 * wv + 16) * 32);
    __syncthreads();

    f16x8 af[4], bf[4];
#pragma unroll
    for (int i = 0; i < 4; ++i) {
      int rA = wr * 64 + i * 16 + (lane & 15);
      int sA = (lane >> 4) ^ ((rA >> 1) & 3);
      af[i] = *(const f16x8*)&As[rA * 32 + sA * 8];
      int rB = wc * 64 + i * 16 + (lane & 15);
      int sB = (lane >> 4) ^ ((rB >> 1) & 3);
      bf[i] = *(const f16x8*)&Bs[rB * 32 + sB * 8];
    }
#pragma unroll
    for (int i = 0; i < 4; ++i)
#pragma unroll
      for (int j = 0; j < 4; ++j)
        acc[i][j] = __builtin_amdgcn_mfma_f32_16x16x32_f16(af[i], bf[j], acc[i][j], 0, 0, 0);
  }

#pragma unroll
  for (int i = 0; i < 4; ++i) {
#pragma unroll
    for (int j = 0; j < 4; ++j) {
      int col = n0 + wc * 64 + j * 16 + (lane & 15);
      if (col < Cc) {
        int rbase = m0 + wr * 64 + i * 16 + ((lane >> 4) * 4);
#pragma unroll
        for (int r = 0; r < 4; ++r) {
          int row = rbase + r;
          if (row < Nn) xq[(size_t)row * SQ + col] = (f16)acc[i][j][r];
        }
      }
    }
  }
}

// ---------------- wave-per-node: single-pass gather-FMA, 6 rows in flight ----------------
__global__ __launch_bounds__(256) void k_agg(const f16* __restrict__ xq,
    const uint2* __restrict__ erec,
    const float* __restrict__ a_src, const float* __restrict__ a_dst,
    const int* __restrict__ offs,
    const float* __restrict__ bias, const float* __restrict__ lin_w,
    const float* __restrict__ lin_b, float* __restrict__ out) {
  __shared__ float sAgg[4][600];
  int tid = threadIdx.x, wv = tid >> 6, ln = tid & 63;
  int n = blockIdx.x * 4 + wv;
  int beg = offs[n], deg = offs[n + 1] - beg;
  float2 adv = *(const float2*)(a_dst + 2 * n);
  float2 asv = *(const float2*)(a_src + 2 * n);
  float sw0 = __expf(lrelu(asv.x + adv.x));
  float sw1 = __expf(lrelu(asv.y + adv.y));

  float acc[12] = {};
  float t0 = 0.f, t1 = 0.f;  // denominators, accumulated redundantly on all lanes
  auto unpack = [](unsigned w, float& e0, float& e1) {
    unsigned short q0 = (unsigned short)(w & 0xffff), q1 = (unsigned short)(w >> 16);
    f16 h0, h1;
    __builtin_memcpy(&h0, &q0, 2);
    __builtin_memcpy(&h1, &q1, 2);
    e0 = (float)h0; e1 = (float)h1;
  };
  auto addrow = [&](const f16* row, float p0, float p1) {
#pragma unroll
    for (int k = 0; k < 3; ++k) {
      int c = 4 * ln + 256 * k;  // head split at 300 is 4-aligned
      if (c < Cc) {
        f16x4 hv = *(const f16x4*)(row + c);
        float p = (c < Dd) ? p0 : p1;
        acc[4 * k + 0] += p * (float)hv[0];
        acc[4 * k + 1] += p * (float)hv[1];
        acc[4 * k + 2] += p * (float)hv[2];
        acc[4 * k + 3] += p * (float)hv[3];
      }
    }
  };

  int j = 0;
  for (; j + 6 <= deg; j += 6) {  // 6 rows in flight (18 row-bursts outstanding)
    uint2 rr[6];
#pragma unroll
    for (int q = 0; q < 6; ++q) rr[q] = erec[beg + j + q];
    float ev[6][2];
#pragma unroll
    for (int q = 0; q < 6; ++q) { unpack(rr[q].y, ev[q][0], ev[q][1]); t0 += ev[q][0]; t1 += ev[q][1]; }
#pragma unroll
    for (int q = 0; q < 6; ++q) addrow(xq + (size_t)rr[q].x * SQ, ev[q][0], ev[q][1]);
  }
  for (; j + 2 <= deg; j += 2) {
    uint2 r0 = erec[beg + j], r1 = erec[beg + j + 1];
    float e00, e01, e10, e11;
    unpack(r0.y, e00, e01); unpack(r1.y, e10, e11);
    t0 += e00 + e10; t1 += e01 + e11;
    addrow(xq + (size_t)r0.x * SQ, e00, e01);
    addrow(xq + (size_t)r1.x * SQ, e10, e11);
  }
  if (j < deg) {
    uint2 r = erec[beg + j];
    float e0, e1;
    unpack(r.y, e0, e1);
    t0 += e0; t1 += e1;
    addrow(xq + (size_t)r.x * SQ, e0, e1);
  }
  addrow(xq + (size_t)n * SQ, sw0, sw1);  // self-loop (unnormalized)

  float inv0 = 1.f / (t0 + sw0), inv1 = 1.f / (t1 + sw1);
#pragma unroll
  for (int k = 0; k < 3; ++k) {
    int c = 4 * ln + 256 * k;
    if (c < Cc) {
      float p = (c < Dd) ? inv0 : inv1;
#pragma unroll
      for (int q = 0; q < 4; ++q) sAgg[wv][c + q] = acc[4 * k + q] * p;
    }
  }
  __syncthreads();

  float part = 0.f;
#pragma unroll
  for (int k = 0; k < 5; ++k) {
    int d = ln + 64 * k;
    if (d < Dd) {
      float v = 0.5f * (sAgg[wv][d] + sAgg[wv][d + Dd]) + bias[d];
      v = fmaxf(v, 0.f);
      part += v * lin_w[d];
    }
  }
  for (int o = 32; o > 0; o >>= 1) part += __shfl_xor(part, o, 64);
  if (ln == 0) out[n] = part + lin_b[0];
}

extern "C" void kernel_launch(void* const* d_in, const int* in_sizes, int n_in,
                              void* d_out, int out_size, void* d_ws, size_t ws_size,
                              hipStream_t stream) {
  const float* x       = (const float*)d_in[0];
  const int*   ei      = (const int*)d_in[1];
  const float* W       = (const float*)d_in[2];
  const float* att_src = (const float*)d_in[3];
  const float* att_dst = (const float*)d_in[4];
  const float* bias    = (const float*)d_in[5];
  const float* lin_w   = (const float*)d_in[6];
  const float* lin_b   = (const float*)d_in[7];
  float* out = (float*)d_out;

  char* ws = (char*)d_ws;
  size_t off = 0;
  auto alloc = [&](size_t bytes) {
    void* p = ws + off;
    off = (off + bytes + 255) & ~(size_t)255;
    return p;
  };
  f16*   xq    = (f16*)alloc((size_t)Nn * SQ * 2);
  f16*   xh    = (f16*)alloc((size_t)MP * KP * 2);
  f16*   Wh    = (f16*)alloc((size_t)NP * KP * 2);
  float* vatt  = (float*)alloc((size_t)Dd * 4 * 4);
  float* a_src = (float*)alloc((size_t)Nn * Hh * 4);
  float* a_dst = (float*)alloc((size_t)Nn * Hh * 4);
  int*   cnt   = (int*)alloc((size_t)Nn * 4);
  int*   offs  = (int*)alloc((size_t)(Nn + 1) * 4);
  unsigned short* rk = (unsigned short*)alloc((size_t)Ee * 2);
  uint2* erec  = (uint2*)alloc((size_t)Ee * 8);

  k_pre2<<<NP * (KP / 4) / 256, 256, 0, stream>>>(W, att_src, att_dst, Wh, vatt, cnt);
  k_pre1<<<MP / 4, 256, 0, stream>>>(x, vatt, ei, xh, a_src, a_dst, cnt, rk);
  k_scan<<<1, 1024, 0, stream>>>(cnt, offs);
  k_mid<<<MMB + (Ee + 255) / 256, 256, 0, stream>>>(xh, Wh, xq, ei, a_src, a_dst, offs, rk, erec);
  k_agg<<<Nn / 4, 256, 0, stream>>>(xq, erec, a_src, a_dst, offs, bias, lin_w, lin_b, out);
}